// Round 1
// baseline (1626.265 us; speedup 1.0000x reference)
//
#include <hip/hip_runtime.h>

#define BB 64
#define SS 2048
#define II 128
#define HH 256
#define OO 128

// ---------------------------------------------------------------------------
// Prep: transpose W_ih -> [I][H], W_fc -> [H][O], combine biases.
// ---------------------------------------------------------------------------
__global__ void prep_kernel(const float* __restrict__ W_ih, const float* __restrict__ b_ih,
                            const float* __restrict__ b_hh, const float* __restrict__ W_fc,
                            float* __restrict__ wihT, float* __restrict__ wfcT,
                            float* __restrict__ biasc) {
    int idx = blockIdx.x * 256 + threadIdx.x;
    if (idx < HH * II) {            // W_ih [H][I] -> wihT [I][H]
        int j = idx / II, k = idx % II;
        wihT[k * HH + j] = W_ih[idx];
    }
    if (idx < OO * HH) {            // W_fc [O][H] -> wfcT [H][O]
        int j = idx / HH, k = idx % HH;
        wfcT[k * OO + j] = W_fc[idx];
    }
    if (idx < HH) biasc[idx] = b_ih[idx] + b_hh[idx];
}

// ---------------------------------------------------------------------------
// Generic row-major GEMM: C[r][j] = sum_k A[r][k] * Wt[k][j] + bias[j]
// 256 threads, 8x8 micro-tile per thread. KD%64==0, NR%RT==0.
// K1: KD=128, JD=256, RT=64  (xproj)   K3: KD=256, JD=128, RT=128 (output)
// ---------------------------------------------------------------------------
template<int KD, int JD, int RT>
__global__ __launch_bounds__(256, 2)
void gemm_rk(const float* __restrict__ A, const float* __restrict__ Wt,
             const float* __restrict__ bias, float* __restrict__ C) {
    constexpr int KT = 64;
    constexpr int TJ = JD / 8;      // threads along j
    constexpr int TR = RT / 8;      // threads along r  (TJ*TR == 256)
    static_assert(TJ * TR == 256, "bad tiling");

    __shared__ __align__(16) float a_lds[RT][KT];
    __shared__ __align__(16) float w_lds[KT][JD];

    const int tid = threadIdx.x;
    const int tj = tid % TJ;
    const int tr = tid / TJ;
    const long r0 = (long)blockIdx.x * RT;

    float acc[8][8];
#pragma unroll
    for (int r = 0; r < 8; ++r)
#pragma unroll
        for (int j = 0; j < 8; ++j) acc[r][j] = 0.0f;

    for (int kt = 0; kt < KD; kt += KT) {
        // stage A tile (coalesced, natural [r][k] layout)
        {
            constexpr int NF4 = RT * KT / 4;
#pragma unroll
            for (int f = 0; f < NF4 / 256; ++f) {
                int fl = f * 256 + tid;
                int rr = fl / (KT / 4), kk4 = fl % (KT / 4);
                *(float4*)&a_lds[rr][kk4 * 4] =
                    *(const float4*)&A[(r0 + rr) * KD + kt + kk4 * 4];
            }
        }
        // stage W tile (coalesced, [k][j] layout)
        {
            constexpr int NF4 = KT * JD / 4;
#pragma unroll
            for (int f = 0; f < NF4 / 256; ++f) {
                int fl = f * 256 + tid;
                int kk = fl / (JD / 4), jj4 = fl % (JD / 4);
                *(float4*)&w_lds[kk][jj4 * 4] =
                    *(const float4*)&Wt[(long)(kt + kk) * JD + jj4 * 4];
            }
        }
        __syncthreads();

#pragma unroll 4
        for (int k4 = 0; k4 < KT; k4 += 4) {
            float4 xv[8];
#pragma unroll
            for (int r = 0; r < 8; ++r)
                xv[r] = *(const float4*)&a_lds[tr * 8 + r][k4];
#pragma unroll
            for (int i = 0; i < 4; ++i) {
                float4 wa = *(const float4*)&w_lds[k4 + i][tj * 8];
                float4 wb = *(const float4*)&w_lds[k4 + i][tj * 8 + 4];
#pragma unroll
                for (int r = 0; r < 8; ++r) {
                    float xs = (i == 0) ? xv[r].x : (i == 1) ? xv[r].y
                             : (i == 2) ? xv[r].z : xv[r].w;
                    acc[r][0] = fmaf(xs, wa.x, acc[r][0]);
                    acc[r][1] = fmaf(xs, wa.y, acc[r][1]);
                    acc[r][2] = fmaf(xs, wa.z, acc[r][2]);
                    acc[r][3] = fmaf(xs, wa.w, acc[r][3]);
                    acc[r][4] = fmaf(xs, wb.x, acc[r][4]);
                    acc[r][5] = fmaf(xs, wb.y, acc[r][5]);
                    acc[r][6] = fmaf(xs, wb.z, acc[r][6]);
                    acc[r][7] = fmaf(xs, wb.w, acc[r][7]);
                }
            }
        }
        __syncthreads();
    }

    // epilogue: + bias, coalesced float4 stores
    float4 b0 = *(const float4*)&bias[tj * 8];
    float4 b1 = *(const float4*)&bias[tj * 8 + 4];
#pragma unroll
    for (int r = 0; r < 8; ++r) {
        long row = r0 + tr * 8 + r;
        float4 o0, o1;
        o0.x = acc[r][0] + b0.x; o0.y = acc[r][1] + b0.y;
        o0.z = acc[r][2] + b0.z; o0.w = acc[r][3] + b0.w;
        o1.x = acc[r][4] + b1.x; o1.y = acc[r][5] + b1.y;
        o1.z = acc[r][6] + b1.z; o1.w = acc[r][7] + b1.w;
        *(float4*)&C[row * JD + tj * 8]     = o0;
        *(float4*)&C[row * JD + tj * 8 + 4] = o1;
    }
}

// ---------------------------------------------------------------------------
// Sequential scan: h_t = tanh(xp_t + h_{t-1} @ W_hh^T), in-place over xproj.
// 64 blocks (one per batch) x 512 threads.
// Thread (og, kg): outputs j = og*4..og*4+3, k-slice kg*32..kg*32+31.
// W_hh rows held in registers (128 VGPR); h broadcast from LDS; 8-way
// partial reduce through LDS; xproj prefetched 2 steps ahead.
// ---------------------------------------------------------------------------
__global__ __launch_bounds__(512, 2)
void rnn_scan(const float* __restrict__ W_hh, float* __restrict__ hid) {
    const int b = blockIdx.x;
    const int tid = threadIdx.x;
    const int og = tid & 63;        // output group
    const int kg = tid >> 6;        // k group, 0..7

    __shared__ __align__(16) float h_lds[HH];
    __shared__ __align__(16) float part[8][HH];

    // load weights: w[g][i4] = W_hh[og*4+g][kg*32 + i4*4 .. +3]
    float4 w[4][8];
#pragma unroll
    for (int g = 0; g < 4; ++g)
#pragma unroll
        for (int i4 = 0; i4 < 8; ++i4)
            w[g][i4] = *(const float4*)&W_hh[(og * 4 + g) * HH + kg * 32 + i4 * 4];

    if (tid < HH) h_lds[tid] = 0.0f;

    float* __restrict__ base = hid + (size_t)b * SS * HH;
    float xp0 = 0.0f, xp1 = 0.0f;
    if (tid < HH) { xp0 = base[tid]; xp1 = base[HH + tid]; }
    __syncthreads();

#pragma unroll 1
    for (int t = 0; t < SS; ++t) {
        // prefetch xproj for t+2 (read-before-overwrite is safe: t+2 > t)
        float xp2 = 0.0f;
        if (tid < HH && t + 2 < SS) xp2 = base[(size_t)(t + 2) * HH + tid];

        // partial dot: acc[g] = sum over this thread's 32 k's
        const float4* hp = (const float4*)&h_lds[kg * 32];
        float acc[4] = {0.f, 0.f, 0.f, 0.f};
#pragma unroll
        for (int i4 = 0; i4 < 8; ++i4) {
            float4 hv = hp[i4];
#pragma unroll
            for (int g = 0; g < 4; ++g) {
                acc[g] = fmaf(hv.x, w[g][i4].x, acc[g]);
                acc[g] = fmaf(hv.y, w[g][i4].y, acc[g]);
                acc[g] = fmaf(hv.z, w[g][i4].z, acc[g]);
                acc[g] = fmaf(hv.w, w[g][i4].w, acc[g]);
            }
        }
        *(float4*)&part[kg][og * 4] = make_float4(acc[0], acc[1], acc[2], acc[3]);
        __syncthreads();

        if (tid < HH) {
            float s = xp0;
#pragma unroll
            for (int q = 0; q < 8; ++q) s += part[q][tid];
            // tanh(s) = (e^{2s}-1)/(e^{2s}+1), clamped for overflow safety
            float cx = fminf(fmaxf(s, -15.0f), 15.0f);
            float e = __expf(2.0f * cx);
            float hn = (e - 1.0f) / (e + 1.0f);
            h_lds[tid] = hn;
            base[(size_t)t * HH + tid] = hn;   // overwrite xproj with hidden
        }
        __syncthreads();
        xp0 = xp1; xp1 = xp2;
    }
}

// ---------------------------------------------------------------------------
extern "C" void kernel_launch(void* const* d_in, const int* in_sizes, int n_in,
                              void* d_out, int out_size, void* d_ws, size_t ws_size,
                              hipStream_t stream) {
    const float* x    = (const float*)d_in[0];
    const float* W_ih = (const float*)d_in[1];
    const float* W_hh = (const float*)d_in[2];
    const float* b_ih = (const float*)d_in[3];
    const float* b_hh = (const float*)d_in[4];
    const float* W_fc = (const float*)d_in[5];
    const float* b_fc = (const float*)d_in[6];

    float* out_fc  = (float*)d_out;                          // [B][S][O]
    float* hidden  = (float*)d_out + (size_t)BB * SS * OO;   // [B][S][H]

    float* wihT  = (float*)d_ws;                 // [I][H]  32768 floats
    float* wfcT  = wihT + II * HH;               // [H][O]  32768 floats
    float* biasc = wfcT + HH * OO;               // [H]       256 floats

    const long NR = (long)BB * SS;               // 131072 rows

    // 0) transpose weights + combine bias
    prep_kernel<<<128, 256, 0, stream>>>(W_ih, b_ih, b_hh, W_fc, wihT, wfcT, biasc);

    // 1) xproj = x @ W_ih^T + bias  -> written into the hidden-state region
    gemm_rk<II, HH, 64><<<NR / 64, 256, 0, stream>>>(x, wihT, biasc, hidden);

    // 2) sequential recurrence, in place over the hidden region
    rnn_scan<<<BB, 512, 0, stream>>>(W_hh, hidden);

    // 3) outputs = hidden @ W_fc^T + b_fc
    gemm_rk<HH, OO, 128><<<NR / 128, 256, 0, stream>>>(hidden, wfcT, b_fc, out_fc);
}